// Round 15
// baseline (54.874 us; speedup 1.0000x reference)
//
#include <hip/hip_runtime.h>
#include <hip/hip_bf16.h>
#include <stdint.h>

#define H_NUM 16
#define S_LEN 2048
#define D_DIM 128
#define WIN   512
#define NWG   256                       // 16 heads x 16 q-groups(128 rows)
#define LOG2E 1.4426950408889634f

typedef __attribute__((ext_vector_type(8)))  _Float16 half8;
typedef __attribute__((ext_vector_type(2)))  __fp16   fp16x2;
typedef __attribute__((ext_vector_type(16))) float f32x16;
typedef __attribute__((ext_vector_type(4)))  unsigned int uint4v;

static __device__ __forceinline__ uint32_t pk16(float a, float b) {
    fp16x2 t = __builtin_amdgcn_cvt_pkrtz(a, b);   // v_cvt_pkrtz_f16_f32
    return __builtin_bit_cast(uint32_t, t);
}
static __device__ __forceinline__ float fexp2(float x) {
#if __has_builtin(__builtin_amdgcn_exp2f)
    return __builtin_amdgcn_exp2f(x);
#else
    return exp2f(x);
#endif
}

// ---- single kernel: flash SWA, KVBLK=64 (2x32 sub-tiles, one barrier/softmax
// rendezvous per 64 keys). In-kernel fp32->fp16 K convert + V transpose during
// reg-staged LDS staging. 8 waves/WG = 4 q-tiles(32) x 2 window-halves.
// mfma_f32_32x32x16_f16: A row=lane&31,k=(lane>>5)*8+e; B col=lane&31,same k;
// C/D col=lane&31, row=(reg&3)+8*(reg>>2)+4*(lane>>5).
// K LDS [64][256B] XOR-swizzled both sides (G21); V LDS 2x slot-major [4][128][16B].
__global__ __launch_bounds__(512, 2) void swa_fwd(
    const float* __restrict__ Q, const float* __restrict__ K,
    const float* __restrict__ V, float* __restrict__ O)
{
    __shared__ __align__(16) char arena[131072];
    char* ksL = arena;                          // [2][16384] K low
    char* vsL = arena + 32768;                  // [2][16384] V low
    char* ksH = arena + 65536;                  // [2][16384] K high
    char* vsH = arena + 98304;                  // [2][16384] V high
    float* mrg_o  = (float*)arena;              // [4][64][68] (post-loop alias)
    float* mrg_ml = (float*)(arena + 69632);    // [4][64][2]

    int bid = blockIdx.x;
    int wid = ((bid & 7) << 5) | (bid >> 3);    // XCD-bijective (256%8==0)
    int h    = wid >> 4;
    int q0wg = (wid & 15) << 7;

    int tid  = threadIdx.x;
    int wv   = tid >> 6;
    int lane = tid & 63;
    int qn = lane & 31;
    int hi = lane >> 5;
    int qsel = wv & 3;
    int hseg = wv >> 2;
    int q0 = q0wg + qsel * 32;

    const float* Qh = Q + ((size_t)h << 18);
    const float* Kg = K + ((size_t)h << 18);
    const float* Vg = V + ((size_t)h << 18);
    float*       Oh = O + ((size_t)h << 18);

    // staging thread maps (512 threads cover one 8KB fp16 32-key sub-tile/call)
    int tK_r = tid >> 4;                        // K row 0..31 (sub-tile local)
    int tK_d = (tid & 15) * 8;                  // K d0
    int tK_byte = tK_r * 256 + (((tid & 15) * 16) ^ ((tK_r & 7) << 4));
    int tV_d = (tid >> 4) * 4;                  // V d0 0..124
    int tV_s = (tid & 15) * 2;                  // V s0 0..30 (even, sub-tile local)
    int tV_byte = (tV_s >> 3) * 2048 + tV_d * 16 + (tV_s & 7) * 2;

    // SUB = 0/1 selects the 32-key half: global rows +32*SUB, LDS +8192*SUB
#define K_LOAD(A0, A1, KB_, SUB) do {                                          \
        const float* sp_ = Kg + ((size_t)((KB_) + 32*(SUB) + tK_r) << 7) + tK_d;\
        A0 = *reinterpret_cast<const float4*>(sp_);                            \
        A1 = *reinterpret_cast<const float4*>(sp_ + 4); } while (0)
#define K_WRITE(KS, BUF, A0, A1, SUB) do {                                     \
        uint4v u_;                                                             \
        u_[0] = pk16(A0.x, A0.y); u_[1] = pk16(A0.z, A0.w);                    \
        u_[2] = pk16(A1.x, A1.y); u_[3] = pk16(A1.z, A1.w);                    \
        *reinterpret_cast<uint4v*>((KS) + (BUF) * 16384 + (SUB) * 8192 + tK_byte) = u_; } while (0)
#define V_LOAD(A0, A1, KB_, SUB) do {                                          \
        const float* sp_ = Vg + ((size_t)((KB_) + 32*(SUB) + tV_s) << 7) + tV_d;\
        A0 = *reinterpret_cast<const float4*>(sp_);                            \
        A1 = *reinterpret_cast<const float4*>(sp_ + D_DIM); } while (0)
#define V_WRITE(VS, BUF, A0, A1, SUB) do {                                     \
        char* b_ = (VS) + (BUF) * 16384 + (SUB) * 8192 + tV_byte;              \
        *reinterpret_cast<uint32_t*>(b_)      = pk16(A0.x, A1.x);              \
        *reinterpret_cast<uint32_t*>(b_ + 16) = pk16(A0.y, A1.y);              \
        *reinterpret_cast<uint32_t*>(b_ + 32) = pk16(A0.z, A1.z);              \
        *reinterpret_cast<uint32_t*>(b_ + 48) = pk16(A0.w, A1.w); } while (0)

    // Q fragments, pre-scaled by log2e (exp2-domain softmax)
    half8 qa[8];
    const float* qrow = Qh + ((size_t)(q0 + qn) << 7) + hi * 8;
    #pragma unroll
    for (int c = 0; c < 8; ++c) {
        float4 a0 = *reinterpret_cast<const float4*>(qrow + c * 16);
        float4 a1 = *reinterpret_cast<const float4*>(qrow + c * 16 + 4);
        qa[c] = (half8){(_Float16)(a0.x * LOG2E), (_Float16)(a0.y * LOG2E),
                        (_Float16)(a0.z * LOG2E), (_Float16)(a0.w * LOG2E),
                        (_Float16)(a1.x * LOG2E), (_Float16)(a1.y * LOG2E),
                        (_Float16)(a1.z * LOG2E), (_Float16)(a1.w * LOG2E)};
    }

    f32x16 oacc[4];
    #pragma unroll
    for (int db = 0; db < 4; ++db)
        #pragma unroll
        for (int i = 0; i < 16; ++i) oacc[db][i] = 0.f;
    float m_s = -1e30f, l_s = 0.f;

    int kstart = q0wg - (WIN - 1);
    if (kstart < 0) kstart = 0;
    kstart &= ~63;                       // 64-tile aligned; kend is 128-aligned
    int nt  = ((q0wg + 128) - kstart) >> 6;   // 64-key tiles (2..10)
    int nt0 = (nt + 1) >> 1;
    int ntH = nt - nt0;                  // >= 1
    int iq   = q0 + qn;
    int w_ks = q0 - (WIN - 1);
    int w_ke = q0 + 32;

    // prologue: stage tile 0 of both streams, both sub-tiles
    {
        float4 a0, a1;
        K_LOAD(a0, a1, kstart, 0);             K_WRITE(ksL, 0, a0, a1, 0);
        K_LOAD(a0, a1, kstart, 1);             K_WRITE(ksL, 0, a0, a1, 1);
        K_LOAD(a0, a1, kstart + nt0 * 64, 0);  K_WRITE(ksH, 0, a0, a1, 0);
        K_LOAD(a0, a1, kstart + nt0 * 64, 1);  K_WRITE(ksH, 0, a0, a1, 1);
        V_LOAD(a0, a1, kstart, 0);             V_WRITE(vsL, 0, a0, a1, 0);
        V_LOAD(a0, a1, kstart, 1);             V_WRITE(vsL, 0, a0, a1, 1);
        V_LOAD(a0, a1, kstart + nt0 * 64, 0);  V_WRITE(vsH, 0, a0, a1, 0);
        V_LOAD(a0, a1, kstart + nt0 * 64, 1);  V_WRITE(vsH, 0, a0, a1, 1);
    }

    int my_cnt = hseg ? ntH : nt0;
    for (int it = 0; it < nt0; ++it) {
        int cur = it & 1, nxt = cur ^ 1;
        __syncthreads();   // publishes buf[cur]; all prev reads drained

        bool hl = (it + 1 < nt0), hh = (it + 1 < ntH);   // WG-uniform
        // issue next-tile K loads early: latency hides under QK^T
        float4 kl0a, kl1a, kl0b, kl1b, kh0a, kh1a, kh0b, kh1b;
        if (hl) { K_LOAD(kl0a, kl1a, kstart + (it + 1) * 64, 0);
                  K_LOAD(kl0b, kl1b, kstart + (it + 1) * 64, 1); }
        if (hh) { K_LOAD(kh0a, kh1a, kstart + (nt0 + it + 1) * 64, 0);
                  K_LOAD(kh0b, kh1b, kstart + (nt0 + it + 1) * 64, 1); }

        int mt = (hseg ? nt0 : 0) + it;
        int kb = kstart + mt * 64;
        bool act = (it < my_cnt) && (kb < w_ke) && (kb + 64 > w_ks);
        const char* ksb = (hseg ? ksH : ksL) + cur * 16384;
        const char* vsb = (hseg ? vsH : vsL) + cur * 16384;

        f32x16 sacc0, sacc1;
        if (act) {
            #pragma unroll
            for (int i = 0; i < 16; ++i) { sacc0[i] = 0.f; sacc1[i] = 0.f; }
            int sw = (qn & 7) << 4;
            // two independent 8-MFMA chains (ILP across sub-tiles)
            #pragma unroll
            for (int c = 0; c < 8; ++c) {
                half8 ka = *reinterpret_cast<const half8*>(
                    ksb + qn * 256 + ((c * 32 + hi * 16) ^ sw));
                half8 kbq = *reinterpret_cast<const half8*>(
                    ksb + 8192 + qn * 256 + ((c * 32 + hi * 16) ^ sw));
                sacc0 = __builtin_amdgcn_mfma_f32_32x32x16_f16(ka,  qa[c], sacc0, 0, 0, 0);
                sacc1 = __builtin_amdgcn_mfma_f32_32x32x16_f16(kbq, qa[c], sacc1, 0, 0, 0);
            }
        }

        // write next K tiles (loads done by now); issue V loads for next tile
        if (hl) { K_WRITE(ksL, nxt, kl0a, kl1a, 0); K_WRITE(ksL, nxt, kl0b, kl1b, 1); }
        if (hh) { K_WRITE(ksH, nxt, kh0a, kh1a, 0); K_WRITE(ksH, nxt, kh0b, kh1b, 1); }
        float4 vl0a, vl1a, vl0b, vl1b, vh0a, vh1a, vh0b, vh1b;
        if (hl) { V_LOAD(vl0a, vl1a, kstart + (it + 1) * 64, 0);
                  V_LOAD(vl0b, vl1b, kstart + (it + 1) * 64, 1); }
        if (hh) { V_LOAD(vh0a, vh1a, kstart + (nt0 + it + 1) * 64, 0);
                  V_LOAD(vh0b, vh1b, kstart + (nt0 + it + 1) * 64, 1); }

        if (act) {
            // mask both sub-tiles into p[32] (interior skip per sub-tile)
            float p[32];
            bool full0 = (kb      >= q0 - 480) && (kb      <= q0 - 31);
            bool full1 = (kb + 32 >= q0 - 480) && (kb + 32 <= q0 - 31);
            if (full0) {
                #pragma unroll
                for (int r = 0; r < 16; ++r) p[r] = sacc0[r];
            } else {
                #pragma unroll
                for (int r = 0; r < 16; ++r) {
                    int j = kb + (r & 3) + 8 * (r >> 2) + 4 * hi;
                    p[r] = ((j <= iq) && (j + WIN > iq)) ? sacc0[r] : -1e30f;
                }
            }
            if (full1) {
                #pragma unroll
                for (int r = 0; r < 16; ++r) p[16 + r] = sacc1[r];
            } else {
                #pragma unroll
                for (int r = 0; r < 16; ++r) {
                    int j = kb + 32 + (r & 3) + 8 * (r >> 2) + 4 * hi;
                    p[16 + r] = ((j <= iq) && (j + WIN > iq)) ? sacc1[r] : -1e30f;
                }
            }
            // row max over all 32 (max3 tree) + single pair exchange
            float t0 = fmaxf(fmaxf(p[0], p[1]), p[2]);
            float t1 = fmaxf(fmaxf(p[3], p[4]), p[5]);
            float t2 = fmaxf(fmaxf(p[6], p[7]), p[8]);
            float t3 = fmaxf(fmaxf(p[9], p[10]), p[11]);
            float t4 = fmaxf(fmaxf(p[12], p[13]), p[14]);
            float t5 = fmaxf(fmaxf(p[15], p[16]), p[17]);
            float t6 = fmaxf(fmaxf(p[18], p[19]), p[20]);
            float t7 = fmaxf(fmaxf(p[21], p[22]), p[23]);
            float t8 = fmaxf(fmaxf(p[24], p[25]), p[26]);
            float t9 = fmaxf(fmaxf(p[27], p[28]), p[29]);
            float ta = fmaxf(p[30], p[31]);
            float tm = fmaxf(fmaxf(fmaxf(fmaxf(t0, t1), fmaxf(t2, t3)),
                                   fmaxf(fmaxf(t4, t5), fmaxf(t6, t7))),
                             fmaxf(fmaxf(t8, t9), ta));
            tm = fmaxf(tm, __shfl_xor(tm, 32));

            // T13 defer-max (forced rescale wipes fresh-lane junk)
            if (!__all(tm - m_s <= 11.5424f)) {
                float mn = fmaxf(m_s, tm);
                float scale = fexp2(m_s - mn);
                m_s = mn;
                l_s *= scale;
                #pragma unroll
                for (int r = 0; r < 16; ++r) {
                    float sr = __shfl(scale, (r & 3) + 8 * (r >> 2) + 4 * hi);
                    oacc[0][r] *= sr; oacc[1][r] *= sr;
                    oacc[2][r] *= sr; oacc[3][r] *= sr;
                }
            }
            #pragma unroll
            for (int r = 0; r < 32; ++r) p[r] = fexp2(p[r] - m_s);
            {
                float s0 = (p[0] + p[1]) + (p[2] + p[3]);
                float s1 = (p[4] + p[5]) + (p[6] + p[7]);
                float s2 = (p[8] + p[9]) + (p[10] + p[11]);
                float s3 = (p[12] + p[13]) + (p[14] + p[15]);
                float s4 = (p[16] + p[17]) + (p[18] + p[19]);
                float s5 = (p[20] + p[21]) + (p[22] + p[23]);
                float s6 = (p[24] + p[25]) + (p[26] + p[27]);
                float s7 = (p[28] + p[29]) + (p[30] + p[31]);
                l_s += ((s0 + s1) + (s2 + s3)) + ((s4 + s5) + (s6 + s7));
            }

            // P -> PV A-frags in-register (per sub-tile s: pa[2s], pa[2s+1])
            half8 pa[4];
            #pragma unroll
            for (int s = 0; s < 2; ++s)
                #pragma unroll
                for (int c = 0; c < 2; ++c) {
                    const float* ps = p + 16 * s + 8 * c;
                    uint32_t u0 = pk16(ps[0], ps[1]);
                    uint32_t u1 = pk16(ps[2], ps[3]);
                    uint32_t u2 = pk16(ps[4], ps[5]);
                    uint32_t u3 = pk16(ps[6], ps[7]);
                    uint4v fw;
#if __has_builtin(__builtin_amdgcn_permlane32_swap)
                    auto w02 = __builtin_amdgcn_permlane32_swap(u0, u2, false, false);
                    auto w13 = __builtin_amdgcn_permlane32_swap(u1, u3, false, false);
                    fw[0] = (uint32_t)w02[0]; fw[2] = (uint32_t)w02[1];
                    fw[1] = (uint32_t)w13[0]; fw[3] = (uint32_t)w13[1];
#else
                    uint32_t x0 = (uint32_t)__shfl_xor((int)u0, 32);
                    uint32_t x1 = (uint32_t)__shfl_xor((int)u1, 32);
                    uint32_t x2 = (uint32_t)__shfl_xor((int)u2, 32);
                    uint32_t x3 = (uint32_t)__shfl_xor((int)u3, 32);
                    if (hi == 0) { fw[0] = u0; fw[1] = u1; fw[2] = x0; fw[3] = x1; }
                    else         { fw[0] = x2; fw[1] = x3; fw[2] = u2; fw[3] = u3; }
#endif
                    pa[2 * s + c] = __builtin_bit_cast(half8, fw);
                }

            // P @ V: 16 MFMA, 4 independent chains
            #pragma unroll
            for (int db = 0; db < 4; ++db)
                #pragma unroll
                for (int s = 0; s < 2; ++s)
                    #pragma unroll
                    for (int c = 0; c < 2; ++c) {
                        half8 vb8 = *reinterpret_cast<const half8*>(
                            vsb + s * 8192 + (2 * c + hi) * 2048 + (db * 32 + qn) * 16);
                        oacc[db] = __builtin_amdgcn_mfma_f32_32x32x16_f16(pa[2*s+c], vb8, oacc[db], 0, 0, 0);
                    }
        }

        // write next V tiles (loads covered by softmax+PV span)
        if (hl) { V_WRITE(vsL, nxt, vl0a, vl1a, 0); V_WRITE(vsL, nxt, vl0b, vl1b, 1); }
        if (hh) { V_WRITE(vsH, nxt, vh0a, vh1a, 0); V_WRITE(vsH, nxt, vh0b, vh1b, 1); }
    }

    l_s += __shfl_xor(l_s, 32);
    __syncthreads();   // final-iter LDS ops drained before arena alias

    // -------- merge halves (arena aliases dead staging LDS) --------
    if (hseg == 1) {
        float* mo = mrg_o + (size_t)(qsel * 64 + lane) * 68;
        #pragma unroll
        for (int db = 0; db < 4; ++db)
            #pragma unroll
            for (int r = 0; r < 16; ++r) mo[db * 16 + r] = oacc[db][r];
        mrg_ml[(qsel * 64 + lane) * 2 + 0] = m_s;
        mrg_ml[(qsel * 64 + lane) * 2 + 1] = l_s;
    }
    __syncthreads();
    if (hseg == 0) {
        float m1 = mrg_ml[(qsel * 64 + lane) * 2 + 0];
        float l1 = mrg_ml[(qsel * 64 + lane) * 2 + 1];
        float mm = fmaxf(m_s, m1);
        float e0 = fexp2(m_s - mm);
        float e1 = fexp2(m1 - mm);
        float inv = 1.f / (l_s * e0 + l1 * e1);
        float sc0 = e0 * inv, sc1 = e1 * inv;
        const float* mo = mrg_o + (size_t)(qsel * 64 + lane) * 68;
        #pragma unroll
        for (int r = 0; r < 16; ++r) {
            int qr = (r & 3) + 8 * (r >> 2) + 4 * hi;
            float s0r = __shfl(sc0, qr);
            float s1r = __shfl(sc1, qr);
            float* orow = Oh + ((size_t)(q0 + qr) << 7) + qn;
            #pragma unroll
            for (int db = 0; db < 4; ++db)
                orow[db * 32] = oacc[db][r] * s0r + mo[db * 16 + r] * s1r;
        }
    }
#undef K_LOAD
#undef K_WRITE
#undef V_LOAD
#undef V_WRITE
}

extern "C" void kernel_launch(void* const* d_in, const int* in_sizes, int n_in,
                              void* d_out, int out_size, void* d_ws, size_t ws_size,
                              hipStream_t stream) {
    (void)in_sizes; (void)n_in; (void)out_size; (void)d_ws; (void)ws_size;
    const float* q = (const float*)d_in[0];
    const float* k = (const float*)d_in[1];
    const float* v = (const float*)d_in[2];
    // d_in[3] = mask: structural (causal sliding window, W=512) — never read.
    float* o = (float*)d_out;
    hipLaunchKernelGGL(swa_fwd, dim3(NWG), dim3(512), 0, stream, q, k, v, o);
}

// Round 16
// 32.731 us; speedup vs baseline: 1.6765x; 1.6765x over previous
//
#include <hip/hip_runtime.h>
#include <hip/hip_bf16.h>
#include <stdint.h>

#define H_NUM 16
#define S_LEN 2048
#define D_DIM 128
#define WIN   512
#define NWG   256                       // 16 heads x 16 q-groups(128 rows)
#define LOG2E 1.4426950408889634f

typedef __attribute__((ext_vector_type(8)))  _Float16 half8;
typedef __attribute__((ext_vector_type(2)))  __fp16   fp16x2;
typedef __attribute__((ext_vector_type(16))) float f32x16;
typedef __attribute__((ext_vector_type(4)))  unsigned int uint4v;

static __device__ __forceinline__ uint32_t pk16(float a, float b) {
    fp16x2 t = __builtin_amdgcn_cvt_pkrtz(a, b);   // v_cvt_pkrtz_f16_f32
    return __builtin_bit_cast(uint32_t, t);
}
static __device__ __forceinline__ float fexp2(float x) {
#if __has_builtin(__builtin_amdgcn_exp2f)
    return __builtin_amdgcn_exp2f(x);
#else
    return exp2f(x);
#endif
}

// ---- single kernel: flash SWA with in-kernel fp32->fp16 K convert and
// V transpose during LDS staging (r14 structure, KVBLK=32 — KVBLK=64 thrashed
// L2: FETCH 31->103MB, reverted r15). r16 delta: T5 setprio around MFMA only.
// 8 waves/WG = 4 q-tiles(32) x 2 window-halves; 32x32 MFMA; single barrier/iter.
// mfma_f32_32x32x16_f16: A row=lane&31,k=(lane>>5)*8+e; B col=lane&31,same k;
// C/D col=lane&31, row=(reg&3)+8*(reg>>2)+4*(lane>>5).
// K LDS [32][256B] XOR-swizzled BOTH sides (G21); V LDS slot-major [4][128][16B].
__global__ __launch_bounds__(512, 2) void swa_fwd(
    const float* __restrict__ Q, const float* __restrict__ K,
    const float* __restrict__ V, float* __restrict__ O)
{
    __shared__ __align__(16) char arena[71680];
    char* ksL = arena;                          // [2][8192] K low
    char* vsL = arena + 16384;                  // [2][8192] V low
    char* ksH = arena + 32768;                  // [2][8192] K high
    char* vsH = arena + 49152;                  // [2][8192] V high
    float* mrg_o  = (float*)arena;              // [4][64][68] (post-loop alias)
    float* mrg_ml = (float*)(arena + 69632);    // [4][64][2]

    int bid = blockIdx.x;
    int wid = ((bid & 7) << 5) | (bid >> 3);    // XCD-bijective (256%8==0)
    int h    = wid >> 4;
    int q0wg = (wid & 15) << 7;

    int tid  = threadIdx.x;
    int wv   = tid >> 6;
    int lane = tid & 63;
    int qn = lane & 31;
    int hi = lane >> 5;
    int qsel = wv & 3;
    int hseg = wv >> 2;
    int q0 = q0wg + qsel * 32;

    const float* Qh = Q + ((size_t)h << 18);
    const float* Kg = K + ((size_t)h << 18);
    const float* Vg = V + ((size_t)h << 18);
    float*       Oh = O + ((size_t)h << 18);

    // staging thread maps (512 threads cover one 8KB fp16 tile per stream)
    int tK_r = tid >> 4;                        // K row 0..31
    int tK_d = (tid & 15) * 8;                  // K d0
    int tK_byte = tK_r * 256 + (((tid & 15) * 16) ^ ((tK_r & 7) << 4));
    int tV_d = (tid >> 4) * 4;                  // V d0 0..124
    int tV_s = (tid & 15) * 2;                  // V s0 0..30 (even)
    int tV_byte = (tV_s >> 3) * 2048 + tV_d * 16 + (tV_s & 7) * 2;

#define K_LOAD(A0, A1, KB_) do {                                               \
        const float* sp_ = Kg + ((size_t)((KB_) + tK_r) << 7) + tK_d;          \
        A0 = *reinterpret_cast<const float4*>(sp_);                            \
        A1 = *reinterpret_cast<const float4*>(sp_ + 4); } while (0)
#define K_WRITE(KS, BUF, A0, A1) do {                                          \
        uint4v u_;                                                             \
        u_[0] = pk16(A0.x, A0.y); u_[1] = pk16(A0.z, A0.w);                    \
        u_[2] = pk16(A1.x, A1.y); u_[3] = pk16(A1.z, A1.w);                    \
        *reinterpret_cast<uint4v*>((KS) + (BUF) * 8192 + tK_byte) = u_; } while (0)
#define V_LOAD(A0, A1, KB_) do {                                               \
        const float* sp_ = Vg + ((size_t)((KB_) + tV_s) << 7) + tV_d;          \
        A0 = *reinterpret_cast<const float4*>(sp_);                            \
        A1 = *reinterpret_cast<const float4*>(sp_ + D_DIM); } while (0)
#define V_WRITE(VS, BUF, A0, A1) do {                                          \
        char* b_ = (VS) + (BUF) * 8192 + tV_byte;                              \
        *reinterpret_cast<uint32_t*>(b_)      = pk16(A0.x, A1.x);              \
        *reinterpret_cast<uint32_t*>(b_ + 16) = pk16(A0.y, A1.y);              \
        *reinterpret_cast<uint32_t*>(b_ + 32) = pk16(A0.z, A1.z);              \
        *reinterpret_cast<uint32_t*>(b_ + 48) = pk16(A0.w, A1.w); } while (0)

    // Q fragments, pre-scaled by log2e (exp2-domain softmax)
    half8 qa[8];
    const float* qrow = Qh + ((size_t)(q0 + qn) << 7) + hi * 8;
    #pragma unroll
    for (int c = 0; c < 8; ++c) {
        float4 a0 = *reinterpret_cast<const float4*>(qrow + c * 16);
        float4 a1 = *reinterpret_cast<const float4*>(qrow + c * 16 + 4);
        qa[c] = (half8){(_Float16)(a0.x * LOG2E), (_Float16)(a0.y * LOG2E),
                        (_Float16)(a0.z * LOG2E), (_Float16)(a0.w * LOG2E),
                        (_Float16)(a1.x * LOG2E), (_Float16)(a1.y * LOG2E),
                        (_Float16)(a1.z * LOG2E), (_Float16)(a1.w * LOG2E)};
    }

    f32x16 oacc[4];
    #pragma unroll
    for (int db = 0; db < 4; ++db)
        #pragma unroll
        for (int i = 0; i < 16; ++i) oacc[db][i] = 0.f;
    float m_s = -1e30f, l_s = 0.f;

    int kstart = q0wg - (WIN - 1);
    if (kstart < 0) kstart = 0;
    kstart &= ~31;
    int nt  = ((q0wg + 128) - kstart) >> 5;
    int nt0 = (nt + 1) >> 1;
    int ntH = nt - nt0;                  // >= 1
    int iq   = q0 + qn;
    int w_ks = q0 - (WIN - 1);
    int w_ke = q0 + 32;

    // prologue: stage tile 0 of both streams (fp32 load -> cvt -> LDS)
    {
        float4 a0, a1;
        K_LOAD(a0, a1, kstart);             K_WRITE(ksL, 0, a0, a1);
        K_LOAD(a0, a1, kstart + nt0 * 32);  K_WRITE(ksH, 0, a0, a1);
        V_LOAD(a0, a1, kstart);             V_WRITE(vsL, 0, a0, a1);
        V_LOAD(a0, a1, kstart + nt0 * 32);  V_WRITE(vsH, 0, a0, a1);
    }

    int my_cnt = hseg ? ntH : nt0;
    for (int it = 0; it < nt0; ++it) {
        int cur = it & 1, nxt = cur ^ 1;
        __syncthreads();   // publishes buf[cur] writes; all prev reads drained

        bool hl = (it + 1 < nt0), hh = (it + 1 < ntH);   // WG-uniform
        // issue next-tile K loads early: latency hides under QK^T
        float4 kl0, kl1, kh0, kh1;
        if (hl) K_LOAD(kl0, kl1, kstart + (it + 1) * 32);
        if (hh) K_LOAD(kh0, kh1, kstart + (nt0 + it + 1) * 32);

        int mt = (hseg ? nt0 : 0) + it;
        int kb = kstart + mt * 32;
        bool act = (it < my_cnt) && (kb < w_ke) && (kb + 32 > w_ks);
        const char* ksb = (hseg ? ksH : ksL) + cur * 8192;
        const char* vsb = (hseg ? vsH : vsL) + cur * 8192;

        f32x16 sacc;
        if (act) {
            #pragma unroll
            for (int i = 0; i < 16; ++i) sacc[i] = 0.f;
            int sw = (qn & 7) << 4;
            __builtin_amdgcn_s_setprio(1);            // T5: favor MFMA wave
            #pragma unroll
            for (int c = 0; c < 8; ++c) {
                half8 kh = *reinterpret_cast<const half8*>(
                    ksb + qn * 256 + ((c * 32 + hi * 16) ^ sw));
                sacc = __builtin_amdgcn_mfma_f32_32x32x16_f16(kh, qa[c], sacc, 0, 0, 0);
            }
            __builtin_amdgcn_s_setprio(0);
        }

        // write next K tiles (loads done by now); issue V loads for next tile
        if (hl) K_WRITE(ksL, nxt, kl0, kl1);
        if (hh) K_WRITE(ksH, nxt, kh0, kh1);
        float4 vl0, vl1, vh0, vh1;
        if (hl) V_LOAD(vl0, vl1, kstart + (it + 1) * 32);
        if (hh) V_LOAD(vh0, vh1, kstart + (nt0 + it + 1) * 32);

        if (act) {
            // mask (interior skip)
            float p[16];
            bool fullt = (kb >= q0 - 480) && (kb <= q0 - 31);
            if (fullt) {
                #pragma unroll
                for (int r = 0; r < 16; ++r) p[r] = sacc[r];
            } else {
                #pragma unroll
                for (int r = 0; r < 16; ++r) {
                    int j = kb + (r & 3) + 8 * (r >> 2) + 4 * hi;
                    p[r] = ((j <= iq) && (j + WIN > iq)) ? sacc[r] : -1e30f;
                }
            }
            // row max (max3 tree) + pair exchange
            float t0 = fmaxf(fmaxf(p[0], p[1]), p[2]);
            float t1 = fmaxf(fmaxf(p[3], p[4]), p[5]);
            float t2 = fmaxf(fmaxf(p[6], p[7]), p[8]);
            float t3 = fmaxf(fmaxf(p[9], p[10]), p[11]);
            float t4 = fmaxf(fmaxf(p[12], p[13]), p[14]);
            float tm = fmaxf(fmaxf(fmaxf(t0, t1), fmaxf(t2, t3)), fmaxf(t4, p[15]));
            tm = fmaxf(tm, __shfl_xor(tm, 32));

            // T13 defer-max, threshold 8*log2e (forced rescale wipes fresh-lane junk)
            if (!__all(tm - m_s <= 11.5424f)) {
                float mn = fmaxf(m_s, tm);
                float scale = fexp2(m_s - mn);
                m_s = mn;
                l_s *= scale;
                #pragma unroll
                for (int r = 0; r < 16; ++r) {
                    float sr = __shfl(scale, (r & 3) + 8 * (r >> 2) + 4 * hi);
                    oacc[0][r] *= sr; oacc[1][r] *= sr;
                    oacc[2][r] *= sr; oacc[3][r] *= sr;
                }
            }
            #pragma unroll
            for (int r = 0; r < 16; ++r) p[r] = fexp2(p[r] - m_s);
            {
                float s0 = (p[0] + p[1]) + (p[2] + p[3]);
                float s1 = (p[4] + p[5]) + (p[6] + p[7]);
                float s2 = (p[8] + p[9]) + (p[10] + p[11]);
                float s3 = (p[12] + p[13]) + (p[14] + p[15]);
                l_s += (s0 + s1) + (s2 + s3);
            }

            // P -> PV A-frags in-register (pk + partner exchange)
            half8 pa[2];
            #pragma unroll
            for (int c = 0; c < 2; ++c) {
                uint32_t u0 = pk16(p[8*c+0], p[8*c+1]);
                uint32_t u1 = pk16(p[8*c+2], p[8*c+3]);
                uint32_t u2 = pk16(p[8*c+4], p[8*c+5]);
                uint32_t u3 = pk16(p[8*c+6], p[8*c+7]);
                uint4v fw;
#if __has_builtin(__builtin_amdgcn_permlane32_swap)
                auto w02 = __builtin_amdgcn_permlane32_swap(u0, u2, false, false);
                auto w13 = __builtin_amdgcn_permlane32_swap(u1, u3, false, false);
                fw[0] = (uint32_t)w02[0]; fw[2] = (uint32_t)w02[1];
                fw[1] = (uint32_t)w13[0]; fw[3] = (uint32_t)w13[1];
#else
                uint32_t x0 = (uint32_t)__shfl_xor((int)u0, 32);
                uint32_t x1 = (uint32_t)__shfl_xor((int)u1, 32);
                uint32_t x2 = (uint32_t)__shfl_xor((int)u2, 32);
                uint32_t x3 = (uint32_t)__shfl_xor((int)u3, 32);
                if (hi == 0) { fw[0] = u0; fw[1] = u1; fw[2] = x0; fw[3] = x1; }
                else         { fw[0] = x2; fw[1] = x3; fw[2] = u2; fw[3] = u3; }
#endif
                pa[c] = __builtin_bit_cast(half8, fw);
            }

            // P @ V
            __builtin_amdgcn_s_setprio(1);            // T5
            #pragma unroll
            for (int db = 0; db < 4; ++db)
                #pragma unroll
                for (int c = 0; c < 2; ++c) {
                    half8 vb8 = *reinterpret_cast<const half8*>(
                        vsb + (2 * c + hi) * 2048 + (db * 32 + qn) * 16);
                    oacc[db] = __builtin_amdgcn_mfma_f32_32x32x16_f16(pa[c], vb8, oacc[db], 0, 0, 0);
                }
            __builtin_amdgcn_s_setprio(0);
        }

        // write next V tiles (loads covered by softmax+PV span)
        if (hl) V_WRITE(vsL, nxt, vl0, vl1);
        if (hh) V_WRITE(vsH, nxt, vh0, vh1);
    }

    l_s += __shfl_xor(l_s, 32);
    __syncthreads();   // final-iter LDS ops drained before arena alias

    // -------- merge halves (arena aliases dead staging LDS) --------
    if (hseg == 1) {
        float* mo = mrg_o + (size_t)(qsel * 64 + lane) * 68;
        #pragma unroll
        for (int db = 0; db < 4; ++db)
            #pragma unroll
            for (int r = 0; r < 16; ++r) mo[db * 16 + r] = oacc[db][r];
        mrg_ml[(qsel * 64 + lane) * 2 + 0] = m_s;
        mrg_ml[(qsel * 64 + lane) * 2 + 1] = l_s;
    }
    __syncthreads();
    if (hseg == 0) {
        float m1 = mrg_ml[(qsel * 64 + lane) * 2 + 0];
        float l1 = mrg_ml[(qsel * 64 + lane) * 2 + 1];
        float mm = fmaxf(m_s, m1);
        float e0 = fexp2(m_s - mm);
        float e1 = fexp2(m1 - mm);
        float inv = 1.f / (l_s * e0 + l1 * e1);
        float sc0 = e0 * inv, sc1 = e1 * inv;
        const float* mo = mrg_o + (size_t)(qsel * 64 + lane) * 68;
        #pragma unroll
        for (int r = 0; r < 16; ++r) {
            int qr = (r & 3) + 8 * (r >> 2) + 4 * hi;
            float s0r = __shfl(sc0, qr);
            float s1r = __shfl(sc1, qr);
            float* orow = Oh + ((size_t)(q0 + qr) << 7) + qn;
            #pragma unroll
            for (int db = 0; db < 4; ++db)
                orow[db * 32] = oacc[db][r] * s0r + mo[db * 16 + r] * s1r;
        }
    }
#undef K_LOAD
#undef K_WRITE
#undef V_LOAD
#undef V_WRITE
}

extern "C" void kernel_launch(void* const* d_in, const int* in_sizes, int n_in,
                              void* d_out, int out_size, void* d_ws, size_t ws_size,
                              hipStream_t stream) {
    (void)in_sizes; (void)n_in; (void)out_size; (void)d_ws; (void)ws_size;
    const float* q = (const float*)d_in[0];
    const float* k = (const float*)d_in[1];
    const float* v = (const float*)d_in[2];
    // d_in[3] = mask: structural (causal sliding window, W=512) — never read.
    float* o = (float*)d_out;
    hipLaunchKernelGGL(swa_fwd, dim3(NWG), dim3(512), 0, stream, q, k, v, o);
}